// Round 1
// baseline (143.140 us; speedup 1.0000x reference)
//
#include <hip/hip_runtime.h>
#include <stdio.h>

// Sizes fixed by the reference
#define H 4
#define B 8192
#define F 64
#define ALPHA 0.2f
#define NT 32            // scan tiles per head
#define TK (B / NT)      // 256 elements per tile
#define NB 2048          // value buckets for the counting "sort"

// -------------------------------------------------------------------------
// K1: h_prime[h,b,o] = sum_i h[b,i] * w[h,i,o];  s[h,b]=hp.a_src, d[h,b]=hp.a_dst
// block = 256 threads (4 waves); each wave owns one row at a time (64 lanes = 64 o's)
__global__ __launch_bounds__(256) void k_hprime(
    const float* __restrict__ h, const float* __restrict__ w,
    const float* __restrict__ a_src, const float* __restrict__ a_dst,
    float* __restrict__ hp, float* __restrict__ s, float* __restrict__ d)
{
  int head = blockIdx.y;
  int row0 = blockIdx.x * 64;
  __shared__ float wl[F * F];   // 16 KB
  __shared__ float hl[64 * F];  // 16 KB
  const float4* wsrc = (const float4*)(w + (size_t)head * F * F);
  const float4* hsrc = (const float4*)(h + (size_t)row0 * F);
  float4* wl4 = (float4*)wl;
  float4* hl4 = (float4*)hl;
  for (int t = threadIdx.x; t < F * F / 4; t += 256) { wl4[t] = wsrc[t]; hl4[t] = hsrc[t]; }
  __syncthreads();
  int o  = threadIdx.x & 63;
  int rb = threadIdx.x >> 6;  // wave id 0..3
  float as = a_src[head * F + o];
  float ad = a_dst[head * F + o];
  for (int rg = 0; rg < 16; ++rg) {
    int r = rg * 4 + rb;
    const float* hr = hl + r * F;
    float acc = 0.f;
#pragma unroll
    for (int i = 0; i < F; ++i) acc = fmaf(hr[i], wl[i * F + o], acc);
    hp[((size_t)head * B + row0 + r) * F + o] = acc;
    float vs = acc * as, vd = acc * ad;
#pragma unroll
    for (int off = 32; off; off >>= 1) { vs += __shfl_down(vs, off); vd += __shfl_down(vd, off); }
    if (o == 0) { s[(size_t)head * B + row0 + r] = vs; d[(size_t)head * B + row0 + r] = vd; }
  }
}

// -------------------------------------------------------------------------
// K2a: per-head min/max of d -> bucket params (dmin, scale)
__global__ __launch_bounds__(1024) void k_minmax(const float* __restrict__ d, float2* __restrict__ bp)
{
  int head = blockIdx.x;
  float mn = 1e30f, mx = -1e30f;
  for (int i = threadIdx.x; i < B; i += 1024) {
    float v = d[(size_t)head * B + i];
    mn = fminf(mn, v); mx = fmaxf(mx, v);
  }
#pragma unroll
  for (int off = 32; off; off >>= 1) { mn = fminf(mn, __shfl_down(mn, off)); mx = fmaxf(mx, __shfl_down(mx, off)); }
  __shared__ float smn[16], smx[16];
  int wid = threadIdx.x >> 6, lane = threadIdx.x & 63;
  if (lane == 0) { smn[wid] = mn; smx[wid] = mx; }
  __syncthreads();
  if (threadIdx.x == 0) {
    for (int i = 1; i < 16; ++i) { mn = fminf(mn, smn[i]); mx = fmaxf(mx, smx[i]); }
    float span = fmaxf(mx - mn, 1e-20f);
    bp[head] = make_float2(mn, (float)NB / span);
  }
}

__device__ __forceinline__ int bucket_of(float x, float dmin, float scale)
{
  int b = (int)((x - dmin) * scale);       // monotone non-decreasing in x
  return min(max(b, 0), NB - 1);
}

// -------------------------------------------------------------------------
// K2b: counting sort by bucket (order within bucket arbitrary — that's OK,
// the boundary bucket is handled element-exactly in k_out).
__global__ __launch_bounds__(1024) void k_bucket(
    const float* __restrict__ d, const float2* __restrict__ bp,
    float* __restrict__ ds, int* __restrict__ is, int* __restrict__ bstart)
{
  int head = blockIdx.x;
  float dmin = bp[head].x, scale = bp[head].y;
  __shared__ int hist[NB];
  __shared__ int buf[NB];
  for (int i = threadIdx.x; i < NB; i += 1024) hist[i] = 0;
  __syncthreads();
  for (int i = threadIdx.x; i < B; i += 1024)
    atomicAdd(&hist[bucket_of(d[(size_t)head * B + i], dmin, scale)], 1);
  __syncthreads();
  // inclusive Hillis-Steele scan, double-buffered
  int* src = hist; int* dst = buf;
  for (int step = 1; step < NB; step <<= 1) {
    for (int i = threadIdx.x; i < NB; i += 1024)
      dst[i] = src[i] + (i >= step ? src[i - step] : 0);
    __syncthreads();
    int* t = src; src = dst; dst = t;
  }
  // exclusive offsets -> bstart + cursors (in dst)
  for (int i = threadIdx.x; i < NB; i += 1024) {
    int ex = i ? src[i - 1] : 0;
    dst[i] = ex;
    bstart[head * (NB + 1) + i] = ex;
  }
  if (threadIdx.x == 0) bstart[head * (NB + 1) + NB] = B;
  __syncthreads();
  for (int i = threadIdx.x; i < B; i += 1024) {
    float v = d[(size_t)head * B + i];
    int b = bucket_of(v, dmin, scale);
    int pos = atomicAdd(&dst[b], 1);
    ds[(size_t)head * B + pos] = v;
    is[(size_t)head * B + pos] = i;
  }
}

// -------------------------------------------------------------------------
// K3 (two passes): hierarchical exclusive prefix sums over bucket-ordered k of
//   chan o      : e^{d_k} * hp[j_k, o]      (wave 0)
//   chan 64+o   : e^{0.2 d_k} * hp[j_k, o]  (wave 1)
//   chan 128/129: e^{d_k} / e^{0.2 d_k}
// WRITE=false: per-tile totals -> tpart.  WRITE=true: write full exclusive prefixes.
template <bool WRITE>
__global__ __launch_bounds__(128) void k_scan_tiles(
    const float* __restrict__ ds, const int* __restrict__ is,
    const float* __restrict__ hp,
    float* __restrict__ tpart,   // [H][NT][130]
    float* __restrict__ PE1, float* __restrict__ PE2,
    float* __restrict__ P1, float* __restrict__ P2)
{
  int head = blockIdx.y, tile = blockIdx.x;
  int o = threadIdx.x & 63, wv = threadIdx.x >> 6;  // wv: 0 -> e^d, 1 -> e^{0.2 d}
  const float* dsh = ds + (size_t)head * B;
  const int*   ish = is + (size_t)head * B;
  const float* hph = hp + (size_t)head * B * F;
  float acc = 0.f, sacc = 0.f;
  if (WRITE) {
    acc  = tpart[(head * NT + tile) * 130 + wv * 64 + o];
    sacc = tpart[(head * NT + tile) * 130 + 128 + wv];
  }
  float* PE = wv ? PE2 : PE1;
  float* P  = wv ? P2 : P1;
  for (int k = tile * TK; k < tile * TK + TK; ++k) {
    float dv = dsh[k];
    float e  = expf(wv ? ALPHA * dv : dv);
    int j = ish[k];
    if (WRITE) {
      PE[((size_t)head * B + k) * F + o] = acc;
      if (o == 0) P[(size_t)head * B + k] = sacc;
    }
    acc = fmaf(e, hph[(size_t)j * F + o], acc);
    sacc += e;
  }
  if (!WRITE) {
    tpart[(head * NT + tile) * 130 + wv * 64 + o] = acc;
    if (o == 0) tpart[(head * NT + tile) * 130 + 128 + wv] = sacc;
  }
}

// K3b: exclusive scan across tiles (in place) + per-head totals
__global__ __launch_bounds__(256) void k_scan_part(
    float* __restrict__ tpart, float* __restrict__ totals)
{
  int head = blockIdx.x;
  int c = threadIdx.x;
  if (c < 130) {
    float run = 0.f;
    for (int t = 0; t < NT; ++t) {
      float* pp = &tpart[(head * NT + t) * 130 + c];
      float v = *pp;
      *pp = run;
      run += v;
    }
    totals[head * 130 + c] = run;
  }
}

// -------------------------------------------------------------------------
// K4: per output row i — bucket lookup + exact boundary-bucket correction.
// out[i, head*64+o] = (e2s*(PE2[Kq]+pl2) + e1s*(TE1-PE1[Kq]-pl1)) / denom + bias
__global__ __launch_bounds__(256) void k_out(
    const float* __restrict__ s, const float* __restrict__ ds, const int* __restrict__ is,
    const float* __restrict__ hp,
    const float* __restrict__ PE1, const float* __restrict__ PE2,
    const float* __restrict__ P1, const float* __restrict__ P2,
    const float* __restrict__ totals, const float2* __restrict__ bp,
    const int* __restrict__ bstart, const float* __restrict__ bias,
    float* __restrict__ out)
{
  int head = blockIdx.y;
  int i = blockIdx.x * 4 + (threadIdx.x >> 6);
  int o = threadIdx.x & 63;
  float si = s[(size_t)head * B + i];
  float t = -si;
  float dmin = bp[head].x, scale = bp[head].y;
  int q = bucket_of(t, dmin, scale);
  int Kq = bstart[head * (NB + 1) + q];
  int Eq = bstart[head * (NB + 1) + q + 1];
  const float* dsh = ds + (size_t)head * B;
  const int*   ish = is + (size_t)head * B;
  const float* hph = hp + (size_t)head * B * F;

  // exact partial sums over the boundary bucket (elements with d < t)
  float pl1 = 0.f, pl2 = 0.f, pl1s = 0.f, pl2s = 0.f;
  for (int k = Kq; k < Eq; ++k) {
    float dv = dsh[k];
    if (dv < t) {
      float e1 = expf(dv), e2 = expf(ALPHA * dv);
      float hv = hph[(size_t)ish[k] * F + o];
      pl1 = fmaf(e1, hv, pl1);
      pl2 = fmaf(e2, hv, pl2);
      pl1s += e1; pl2s += e2;
    }
  }

  float e1s = expf(si), e2s = expf(ALPHA * si);
  float T1  = totals[head * 130 + 128];
  float TE1 = totals[head * 130 + o];
  float TE2 = totals[head * 130 + 64 + o];
  float p1, p2, pe1, pe2;
  if (Kq < B) {
    p1  = P1[(size_t)head * B + Kq];
    p2  = P2[(size_t)head * B + Kq];
    pe1 = PE1[((size_t)head * B + Kq) * F + o];
    pe2 = PE2[((size_t)head * B + Kq) * F + o];
  } else {
    p1 = T1; p2 = totals[head * 130 + 129]; pe1 = TE1; pe2 = TE2;
  }
  float denom = e2s * (p2 + pl2s) + e1s * (T1 - p1 - pl1s);
  float num   = e2s * (pe2 + pl2) + e1s * (TE1 - pe1 - pl1);
  out[(size_t)i * (H * F) + head * F + o] = num / denom + bias[o];
}

// -------------------------------------------------------------------------
extern "C" void kernel_launch(void* const* d_in, const int* in_sizes, int n_in,
                              void* d_out, int out_size, void* d_ws, size_t ws_size,
                              hipStream_t stream)
{
  const float* h     = (const float*)d_in[0];
  const float* w     = (const float*)d_in[1];
  const float* a_src = (const float*)d_in[2];
  const float* a_dst = (const float*)d_in[3];
  const float* bias  = (const float*)d_in[4];
  float* out = (float*)d_out;

  float* p = (float*)d_ws;
  float* hp     = p; p += (size_t)H * B * F;   // 2,097,152
  float* s      = p; p += H * B;               // 32,768
  float* dd     = p; p += H * B;
  float* dsort  = p; p += H * B;
  int*   isort  = (int*)p; p += H * B;
  float* P1     = p; p += H * B;
  float* P2     = p; p += H * B;
  float* PE1    = p; p += (size_t)H * B * F;
  float* PE2    = p; p += (size_t)H * B * F;
  float* tpart  = p; p += H * NT * 130;
  float* totals = p; p += H * 130;
  float2* bp    = (float2*)p; p += 2 * H;
  int* bstart   = (int*)p; p += H * (NB + 1);

  size_t need = (size_t)((char*)p - (char*)d_ws);
  if (ws_size < need) {
    fprintf(stderr, "kernel_launch: ws_size %zu < needed %zu\n", ws_size, need);
    return;  // will fail validation loudly rather than corrupt memory
  }

  k_hprime<<<dim3(B / 64, H), 256, 0, stream>>>(h, w, a_src, a_dst, hp, s, dd);
  k_minmax<<<H, 1024, 0, stream>>>(dd, bp);
  k_bucket<<<H, 1024, 0, stream>>>(dd, bp, dsort, isort, bstart);
  k_scan_tiles<false><<<dim3(NT, H), 128, 0, stream>>>(dsort, isort, hp, tpart, PE1, PE2, P1, P2);
  k_scan_part<<<H, 256, 0, stream>>>(tpart, totals);
  k_scan_tiles<true><<<dim3(NT, H), 128, 0, stream>>>(dsort, isort, hp, tpart, PE1, PE2, P1, P2);
  k_out<<<dim3(B / 4, H), 256, 0, stream>>>(s, dsort, isort, hp, PE1, PE2, P1, P2, totals, bp, bstart, bias, out);
}

// Round 2
// 110.103 us; speedup vs baseline: 1.3001x; 1.3001x over previous
//
#include <hip/hip_runtime.h>
#include <stdio.h>

// Sizes fixed by the reference
#define H 4
#define B 8192
#define F 64
#define ALPHA 0.2f
#define NB 2048          // value buckets for the counting "sort"
#define BSLD 132         // padded row: 64 (e^d*hp) + 64 (e^.2d*hp) + 2 scalars

// -------------------------------------------------------------------------
// K1: h_prime[h,b,o] = sum_i h[b,i] * w[h,i,o];  s[h,b]=hp.a_src, d[h,b]=hp.a_dst
__global__ __launch_bounds__(256) void k_hprime(
    const float* __restrict__ h, const float* __restrict__ w,
    const float* __restrict__ a_src, const float* __restrict__ a_dst,
    float* __restrict__ hp, float* __restrict__ s, float* __restrict__ d)
{
  int head = blockIdx.y;
  int row0 = blockIdx.x * 64;
  __shared__ float wl[F * F];   // 16 KB
  __shared__ float hl[64 * F];  // 16 KB
  const float4* wsrc = (const float4*)(w + (size_t)head * F * F);
  const float4* hsrc = (const float4*)(h + (size_t)row0 * F);
  float4* wl4 = (float4*)wl;
  float4* hl4 = (float4*)hl;
  for (int t = threadIdx.x; t < F * F / 4; t += 256) { wl4[t] = wsrc[t]; hl4[t] = hsrc[t]; }
  __syncthreads();
  int o  = threadIdx.x & 63;
  int rb = threadIdx.x >> 6;  // wave id 0..3
  float as = a_src[head * F + o];
  float ad = a_dst[head * F + o];
  for (int rg = 0; rg < 16; ++rg) {
    int r = rg * 4 + rb;
    const float* hr = hl + r * F;
    float acc = 0.f;
#pragma unroll
    for (int i = 0; i < F; ++i) acc = fmaf(hr[i], wl[i * F + o], acc);
    hp[((size_t)head * B + row0 + r) * F + o] = acc;
    float vs = acc * as, vd = acc * ad;
#pragma unroll
    for (int off = 32; off; off >>= 1) { vs += __shfl_down(vs, off); vd += __shfl_down(vd, off); }
    if (o == 0) { s[(size_t)head * B + row0 + r] = vs; d[(size_t)head * B + row0 + r] = vd; }
  }
}

__device__ __forceinline__ int bucket_of(float x, float dmin, float scale)
{
  int b = (int)((x - dmin) * scale);       // monotone non-decreasing in x
  return min(max(b, 0), NB - 1);
}

// -------------------------------------------------------------------------
// K2: fused per-head prep: minmax -> bucket params -> histogram -> scan ->
//     counting-sort scatter. One 1024-thread block per head.
__global__ __launch_bounds__(1024) void k_prep(
    const float* __restrict__ d, float2* __restrict__ bp,
    float* __restrict__ ds, int* __restrict__ is, int* __restrict__ bstart)
{
  int head = blockIdx.x;
  const float* dh = d + (size_t)head * B;
  __shared__ int hist[NB];
  __shared__ int buf[NB];
  __shared__ float red[34];
  // --- minmax ---
  float mn = 1e30f, mx = -1e30f;
  for (int i = threadIdx.x; i < B; i += 1024) {
    float v = dh[i];
    mn = fminf(mn, v); mx = fmaxf(mx, v);
  }
#pragma unroll
  for (int off = 32; off; off >>= 1) { mn = fminf(mn, __shfl_down(mn, off)); mx = fmaxf(mx, __shfl_down(mx, off)); }
  int wid = threadIdx.x >> 6, lane = threadIdx.x & 63;
  if (lane == 0) { red[2 + wid] = mn; red[18 + wid] = mx; }
  for (int i = threadIdx.x; i < NB; i += 1024) hist[i] = 0;   // zero hist while waiting
  __syncthreads();
  if (threadIdx.x == 0) {
    mn = red[2]; mx = red[18];
    for (int i = 1; i < 16; ++i) { mn = fminf(mn, red[2 + i]); mx = fmaxf(mx, red[18 + i]); }
    float span = fmaxf(mx - mn, 1e-20f);
    red[0] = mn; red[1] = (float)NB / span;
    bp[head] = make_float2(mn, (float)NB / span);
  }
  __syncthreads();
  float dmin = red[0], scale = red[1];
  // --- histogram ---
  for (int i = threadIdx.x; i < B; i += 1024)
    atomicAdd(&hist[bucket_of(dh[i], dmin, scale)], 1);
  __syncthreads();
  // --- inclusive Hillis-Steele scan, double-buffered ---
  int* src = hist; int* dst = buf;
  for (int step = 1; step < NB; step <<= 1) {
    for (int i = threadIdx.x; i < NB; i += 1024)
      dst[i] = src[i] + (i >= step ? src[i - step] : 0);
    __syncthreads();
    int* t = src; src = dst; dst = t;
  }
  // exclusive offsets -> cursors (dst) + bstart
  for (int i = threadIdx.x; i < NB; i += 1024) {
    int ex = i ? src[i - 1] : 0;
    dst[i] = ex;
    bstart[head * (NB + 1) + i] = ex;
  }
  if (threadIdx.x == 0) bstart[head * (NB + 1) + NB] = B;
  __syncthreads();
  // --- scatter (order within bucket arbitrary; boundary bucket is exact in k_out) ---
  for (int i = threadIdx.x; i < B; i += 1024) {
    float v = dh[i];
    int b = bucket_of(v, dmin, scale);
    int pos = atomicAdd(&dst[b], 1);
    ds[(size_t)head * B + pos] = v;
    is[(size_t)head * B + pos] = i;
  }
}

// -------------------------------------------------------------------------
// K3: per-bucket sums. One wave per bucket -> 8192 waves, fully parallel.
//   BS[head][b][o]      = sum_{k in bucket b} e^{d_k}      * hp[j_k, o]
//   BS[head][b][64+o]   = sum_{k in bucket b} e^{0.2 d_k}  * hp[j_k, o]
//   BS[head][b][128/129]= sum e^{d_k} / sum e^{0.2 d_k}
__global__ __launch_bounds__(256) void k_bsum(
    const float* __restrict__ ds, const int* __restrict__ is,
    const float* __restrict__ hp, const int* __restrict__ bstart,
    float* __restrict__ BS)
{
  int head = blockIdx.y;
  int b = blockIdx.x * 4 + (threadIdx.x >> 6);
  int o = threadIdx.x & 63;
  int k0 = bstart[head * (NB + 1) + b];
  int k1 = bstart[head * (NB + 1) + b + 1];
  const float* dsh = ds + (size_t)head * B;
  const int*   ish = is + (size_t)head * B;
  const float* hph = hp + (size_t)head * B * F;
  float a1 = 0.f, a2 = 0.f, s1 = 0.f, s2 = 0.f;
  for (int k = k0; k < k1; ++k) {
    float dv = dsh[k];
    float e1 = expf(dv), e2 = expf(ALPHA * dv);
    float hv = hph[(size_t)ish[k] * F + o];
    a1 = fmaf(e1, hv, a1); a2 = fmaf(e2, hv, a2);
    s1 += e1; s2 += e2;
  }
  float* row = BS + ((size_t)head * NB + b) * BSLD;
  row[o] = a1; row[64 + o] = a2;
  if (o == 0) { row[128] = s1; row[129] = s2; }
}

// -------------------------------------------------------------------------
// K4: in-place exclusive prefix over the NB buckets, per (head, channel).
// 520 independent 1-wave blocks; 32 buckets per lane.
__global__ __launch_bounds__(64) void k_bscan(
    float* __restrict__ BS, float* __restrict__ totals)
{
  int head = blockIdx.y;
  int c = blockIdx.x;       // 0..129
  int lane = threadIdx.x;   // 0..63
  float* base = BS + (size_t)head * NB * BSLD + c;
  int b0 = lane * 32;
  // pass 1: per-lane chunk sum
  float s = 0.f;
  for (int t = 0; t < 32; ++t) s += base[(size_t)(b0 + t) * BSLD];
  // inclusive shuffle scan across lanes -> exclusive offset
  float run = s;
#pragma unroll
  for (int off = 1; off < 64; off <<= 1) {
    float v = __shfl_up(run, off);
    if (lane >= off) run += v;
  }
  float excl = run - s;
  if (lane == 63) totals[head * BSLD + c] = run;
  // pass 2: rewrite chunk as exclusive prefix (column owned exclusively by this block)
  float acc = excl;
  for (int t = 0; t < 32; ++t) {
    float* p = &base[(size_t)(b0 + t) * BSLD];
    float v = *p;
    *p = acc;
    acc += v;
  }
}

// -------------------------------------------------------------------------
// K5: per output row i — bucket-prefix lookup + exact boundary-bucket correction.
__global__ __launch_bounds__(256) void k_out(
    const float* __restrict__ s, const float* __restrict__ ds, const int* __restrict__ is,
    const float* __restrict__ hp, const float* __restrict__ BS,
    const float* __restrict__ totals, const float2* __restrict__ bp,
    const int* __restrict__ bstart, const float* __restrict__ bias,
    float* __restrict__ out)
{
  int head = blockIdx.y;
  int i = blockIdx.x * 4 + (threadIdx.x >> 6);
  int o = threadIdx.x & 63;
  float si = s[(size_t)head * B + i];
  float t = -si;
  float dmin = bp[head].x, scale = bp[head].y;
  int q = bucket_of(t, dmin, scale);
  int Kq = bstart[head * (NB + 1) + q];
  int Eq = bstart[head * (NB + 1) + q + 1];
  const float* dsh = ds + (size_t)head * B;
  const int*   ish = is + (size_t)head * B;
  const float* hph = hp + (size_t)head * B * F;

  // exact partial sums over the boundary bucket (elements with d < t)
  float pl1 = 0.f, pl2 = 0.f, pl1s = 0.f, pl2s = 0.f;
  for (int k = Kq; k < Eq; ++k) {
    float dv = dsh[k];
    if (dv < t) {
      float e1 = expf(dv), e2 = expf(ALPHA * dv);
      float hv = hph[(size_t)ish[k] * F + o];
      pl1 = fmaf(e1, hv, pl1);
      pl2 = fmaf(e2, hv, pl2);
      pl1s += e1; pl2s += e2;
    }
  }

  const float* row = BS + ((size_t)head * NB + q) * BSLD;
  float pe1 = row[o], pe2 = row[64 + o];
  float p1  = row[128], p2 = row[129];
  float e1s = expf(si), e2s = expf(ALPHA * si);
  float T1  = totals[head * BSLD + 128];
  float TE1 = totals[head * BSLD + o];
  float denom = e2s * (p2 + pl2s) + e1s * (T1 - p1 - pl1s);
  float num   = e2s * (pe2 + pl2) + e1s * (TE1 - pe1 - pl1);
  out[(size_t)i * (H * F) + head * F + o] = num / denom + bias[o];
}

// -------------------------------------------------------------------------
extern "C" void kernel_launch(void* const* d_in, const int* in_sizes, int n_in,
                              void* d_out, int out_size, void* d_ws, size_t ws_size,
                              hipStream_t stream)
{
  const float* h     = (const float*)d_in[0];
  const float* w     = (const float*)d_in[1];
  const float* a_src = (const float*)d_in[2];
  const float* a_dst = (const float*)d_in[3];
  const float* bias  = (const float*)d_in[4];
  float* out = (float*)d_out;

  float* p = (float*)d_ws;
  float* hp     = p; p += (size_t)H * B * F;      // 2,097,152
  float* s      = p; p += H * B;
  float* dd     = p; p += H * B;
  float* dsort  = p; p += H * B;
  int*   isort  = (int*)p; p += H * B;
  float* BS     = p; p += (size_t)H * NB * BSLD;  // 1,081,344
  float* totals = p; p += H * BSLD;
  float2* bp    = (float2*)p; p += 2 * H;
  int* bstart   = (int*)p; p += H * (NB + 1);

  size_t need = (size_t)((char*)p - (char*)d_ws);
  if (ws_size < need) {
    fprintf(stderr, "kernel_launch: ws_size %zu < needed %zu\n", ws_size, need);
    return;
  }

  k_hprime<<<dim3(B / 64, H), 256, 0, stream>>>(h, w, a_src, a_dst, hp, s, dd);
  k_prep<<<H, 1024, 0, stream>>>(dd, bp, dsort, isort, bstart);
  k_bsum<<<dim3(NB / 4, H), 256, 0, stream>>>(dsort, isort, hp, bstart, BS);
  k_bscan<<<dim3(130, H), 64, 0, stream>>>(BS, totals);
  k_out<<<dim3(B / 4, H), 256, 0, stream>>>(s, dsort, isort, hp, BS, totals, bp, bstart, bias, out);
}